// Round 1
// baseline (1683.148 us; speedup 1.0000x reference)
//
#include <hip/hip_runtime.h>
#include <hip/hip_bf16.h>
#include <cstdint>

// Problem constants
#define BB 2
#define SS 2048
#define DD 2048
#define HH 16
#define HD 128
#define FF 8192
#define QKVD 6144  // 3*DD

typedef __bf16 bf16x8 __attribute__((ext_vector_type(8)));
typedef float floatx4 __attribute__((ext_vector_type(4)));

#define LOG2E 1.4426950408889634f

__device__ __forceinline__ unsigned short f2bf(float f) {
  unsigned u = __builtin_bit_cast(unsigned, f);
  u += 0x7FFFu + ((u >> 16) & 1u);
  return (unsigned short)(u >> 16);
}
__device__ __forceinline__ float bf2f(unsigned short h) {
  return __builtin_bit_cast(float, (unsigned)h << 16);
}

__device__ __forceinline__ void load_lds_16B(const void* g, void* l) {
  __builtin_amdgcn_global_load_lds(
      (const __attribute__((address_space(1))) unsigned int*)g,
      (__attribute__((address_space(3))) unsigned int*)l, 16, 0, 0);
}

// ---------------- fp32 -> bf16 convert ----------------
__global__ void f32_to_bf16_vec(const float* __restrict__ src,
                                unsigned short* __restrict__ dst, int n4) {
  int i = blockIdx.x * 256 + threadIdx.x;
  if (i < n4) {
    float4 v = ((const float4*)src)[i];
    ushort4 o;
    o.x = f2bf(v.x); o.y = f2bf(v.y); o.z = f2bf(v.z); o.w = f2bf(v.w);
    ((ushort4*)dst)[i] = o;
  }
}

// ---------------- RMSNorm (fp32 in, bf16 out) ----------------
__global__ __launch_bounds__(256) void rmsnorm_bf16(const float* __restrict__ x,
                                                    const float* __restrict__ w,
                                                    unsigned short* __restrict__ xn) {
  const int row = blockIdx.x, tid = threadIdx.x;
  const float4* xr = (const float4*)(x + (size_t)row * DD);
  float4 a = xr[tid], b = xr[tid + 256];
  float ss = a.x * a.x + a.y * a.y + a.z * a.z + a.w * a.w +
             b.x * b.x + b.y * b.y + b.z * b.z + b.w * b.w;
#pragma unroll
  for (int off = 1; off < 64; off <<= 1) ss += __shfl_xor(ss, off);
  __shared__ float red[4];
  if ((tid & 63) == 0) red[tid >> 6] = ss;
  __syncthreads();
  float tot = red[0] + red[1] + red[2] + red[3];
  float sc = rsqrtf(tot * (1.0f / (float)DD) + 1e-5f);
  const float4* wr = (const float4*)w;
  float4 wa = wr[tid], wb = wr[tid + 256];
  ushort4 oa, ob;
  oa.x = f2bf(a.x * sc * wa.x); oa.y = f2bf(a.y * sc * wa.y);
  oa.z = f2bf(a.z * sc * wa.z); oa.w = f2bf(a.w * sc * wa.w);
  ob.x = f2bf(b.x * sc * wb.x); ob.y = f2bf(b.y * sc * wb.y);
  ob.z = f2bf(b.z * sc * wb.z); ob.w = f2bf(b.w * sc * wb.w);
  *(ushort4*)&xn[(size_t)row * DD + tid * 4] = oa;
  *(ushort4*)&xn[(size_t)row * DD + (tid + 256) * 4] = ob;
}

// ---------------- GEMM: C[M,N] = A[M,K] @ Bw[N,K]^T  (bf16 in, fp32 acc) ----
// MODE 0: store bf16
// MODE 1: store bf16 of (acc + bias[col])
// MODE 2: store bf16 of (aux[idx] + relu(acc + bias[col]))   (aux may == Cout)
// MODE 3: store fp32 of (acc + bias[col] + res[idx])
template <int MODE>
__global__ __launch_bounds__(256) void gemm_bt(
    const unsigned short* __restrict__ A, const unsigned short* __restrict__ Bw,
    void* __restrict__ Cout, const float* __restrict__ bias,
    const unsigned short* __restrict__ aux, const float* __restrict__ res,
    int M, int N, int K) {
  __shared__ __align__(16) unsigned short As[128 * 32];
  __shared__ __align__(16) unsigned short Bs[128 * 32];
  const int tid = threadIdx.x;
  const int lane = tid & 63, wave = tid >> 6;
  const int l16 = lane & 15, quad = lane >> 4;
  const int wm = wave & 1, wn = wave >> 1;
  const int m0 = blockIdx.y * 128, n0 = blockIdx.x * 128;

  floatx4 acc[4][4];
#pragma unroll
  for (int i = 0; i < 4; i++)
#pragma unroll
    for (int j = 0; j < 4; j++) acc[i][j] = floatx4{0.f, 0.f, 0.f, 0.f};

  for (int k0 = 0; k0 < K; k0 += 32) {
    __syncthreads();
#pragma unroll
    for (int i = 0; i < 4; i++) {
      const int c = i * 256 + wave * 64 + lane;
      load_lds_16B(A + (size_t)(m0 + (c >> 2)) * K + k0 + (c & 3) * 8,
                   &As[(i * 256 + wave * 64) * 8]);
    }
#pragma unroll
    for (int i = 0; i < 4; i++) {
      const int c = i * 256 + wave * 64 + lane;
      load_lds_16B(Bw + (size_t)(n0 + (c >> 2)) * K + k0 + (c & 3) * 8,
                   &Bs[(i * 256 + wave * 64) * 8]);
    }
    __syncthreads();
    bf16x8 af[4], bfr[4];
#pragma unroll
    for (int mi = 0; mi < 4; mi++)
      af[mi] = *(const bf16x8*)&As[(wm * 64 + mi * 16 + l16) * 32 + quad * 8];
#pragma unroll
    for (int ni = 0; ni < 4; ni++)
      bfr[ni] = *(const bf16x8*)&Bs[(wn * 64 + ni * 16 + l16) * 32 + quad * 8];
#pragma unroll
    for (int mi = 0; mi < 4; mi++)
#pragma unroll
      for (int ni = 0; ni < 4; ni++)
        acc[mi][ni] = __builtin_amdgcn_mfma_f32_16x16x32_bf16(af[mi], bfr[ni],
                                                              acc[mi][ni], 0, 0, 0);
  }

#pragma unroll
  for (int ni = 0; ni < 4; ni++) {
    const int col = n0 + wn * 64 + ni * 16 + l16;
    float bv = 0.0f;
    if constexpr (MODE >= 1) bv = bias[col];
#pragma unroll
    for (int mi = 0; mi < 4; mi++) {
      const int row0 = m0 + wm * 64 + mi * 16 + quad * 4;
#pragma unroll
      for (int r = 0; r < 4; r++) {
        const size_t idx = (size_t)(row0 + r) * N + col;
        float v = acc[mi][ni][r];
        if constexpr (MODE == 0) {
          ((unsigned short*)Cout)[idx] = f2bf(v);
        } else if constexpr (MODE == 1) {
          ((unsigned short*)Cout)[idx] = f2bf(v + bv);
        } else if constexpr (MODE == 2) {
          float t = fmaxf(v + bv, 0.0f) + bf2f(aux[idx]);
          ((unsigned short*)Cout)[idx] = f2bf(t);
        } else {
          ((float*)Cout)[idx] = v + bv + res[idx];
        }
      }
    }
  }
}

// ---------------- Flash causal attention ----------------
// qkv: [B*S, 6144] bf16 rows (q | k | v per head). out: [B][H][S][HD] bf16.
__global__ __launch_bounds__(256) void attn_fwd(const unsigned short* __restrict__ qkv,
                                                unsigned short* __restrict__ out) {
  __shared__ __align__(16) unsigned short Ks[32 * 136];
  __shared__ __align__(16) unsigned short Vt[128 * 40];
  __shared__ __align__(16) unsigned short Ps[4][16 * 40];
  const int tid = threadIdx.x;
  const int lane = tid & 63, wave = tid >> 6;
  const int l16 = lane & 15, quad = lane >> 4;
  const int b = blockIdx.z, h = blockIdx.y;
  const int q0 = blockIdx.x * 64 + wave * 16;

  bf16x8 aq[4];
  {
    const unsigned short* Qp =
        qkv + ((size_t)(b * SS + q0 + l16)) * QKVD + h * HD;
#pragma unroll
    for (int kc = 0; kc < 4; kc++)
      aq[kc] = *(const bf16x8*)(Qp + kc * 32 + quad * 8);
  }

  floatx4 o[8];
#pragma unroll
  for (int i = 0; i < 8; i++) o[i] = floatx4{0.f, 0.f, 0.f, 0.f};
  float m_r[4] = {-1e30f, -1e30f, -1e30f, -1e30f};
  float l_r[4] = {0.f, 0.f, 0.f, 0.f};

  const int ntiles = blockIdx.x * 2 + 2;
  const int srow = tid >> 3, scc = tid & 7;
  const float scale = 0.088388347648318447f;  // 1/sqrt(128)

  for (int t = 0; t < ntiles; t++) {
    const int kv0 = t * 32;
    __syncthreads();
    {
      const unsigned short* Kp =
          qkv + ((size_t)(b * SS + kv0 + srow)) * QKVD + DD + h * HD + scc * 16;
      uint4 ka = *(const uint4*)Kp;
      uint4 kb = *(const uint4*)(Kp + 8);
      *(uint4*)&Ks[srow * 136 + scc * 16] = ka;
      *(uint4*)&Ks[srow * 136 + scc * 16 + 8] = kb;
      const unsigned short* Vp =
          qkv + ((size_t)(b * SS + kv0 + srow)) * QKVD + 2 * DD + h * HD + scc * 16;
      unsigned short vt[16];
      *(uint4*)&vt[0] = *(const uint4*)Vp;
      *(uint4*)&vt[8] = *(const uint4*)(Vp + 8);
#pragma unroll
      for (int i = 0; i < 16; i++) Vt[(scc * 16 + i) * 40 + srow] = vt[i];
    }
    __syncthreads();

    floatx4 s0 = {0.f, 0.f, 0.f, 0.f}, s1 = {0.f, 0.f, 0.f, 0.f};
#pragma unroll
    for (int kc = 0; kc < 4; kc++) {
      bf16x8 bk0 = *(const bf16x8*)&Ks[l16 * 136 + kc * 32 + quad * 8];
      bf16x8 bk1 = *(const bf16x8*)&Ks[(16 + l16) * 136 + kc * 32 + quad * 8];
      s0 = __builtin_amdgcn_mfma_f32_16x16x32_bf16(aq[kc], bk0, s0, 0, 0, 0);
      s1 = __builtin_amdgcn_mfma_f32_16x16x32_bf16(aq[kc], bk1, s1, 0, 0, 0);
    }

    float alpha[4], p0a[4], p1a[4];
#pragma unroll
    for (int r = 0; r < 4; r++) {
      const int qrow = q0 + quad * 4 + r;
      float v0 = s0[r] * scale;
      if (kv0 + l16 > qrow) v0 = -1e30f;
      float v1 = s1[r] * scale;
      if (kv0 + 16 + l16 > qrow) v1 = -1e30f;
      float mxl = fmaxf(v0, v1);
      mxl = fmaxf(mxl, __shfl_xor(mxl, 1));
      mxl = fmaxf(mxl, __shfl_xor(mxl, 2));
      mxl = fmaxf(mxl, __shfl_xor(mxl, 4));
      mxl = fmaxf(mxl, __shfl_xor(mxl, 8));
      float mnew = fmaxf(m_r[r], mxl);
      float al = exp2f((m_r[r] - mnew) * LOG2E);
      float p0 = exp2f((v0 - mnew) * LOG2E);
      float p1 = exp2f((v1 - mnew) * LOG2E);
      float rs = p0 + p1;
      rs += __shfl_xor(rs, 1);
      rs += __shfl_xor(rs, 2);
      rs += __shfl_xor(rs, 4);
      rs += __shfl_xor(rs, 8);
      l_r[r] = l_r[r] * al + rs;
      m_r[r] = mnew;
      alpha[r] = al;
      p0a[r] = p0;
      p1a[r] = p1;
    }
#pragma unroll
    for (int nb = 0; nb < 8; nb++)
#pragma unroll
      for (int r = 0; r < 4; r++) o[nb][r] *= alpha[r];

    unsigned short* Pw = &Ps[wave][0];
#pragma unroll
    for (int r = 0; r < 4; r++) {
      Pw[(quad * 4 + r) * 40 + l16] = f2bf(p0a[r]);
      Pw[(quad * 4 + r) * 40 + 16 + l16] = f2bf(p1a[r]);
    }
    asm volatile("s_waitcnt lgkmcnt(0)" ::: "memory");
    bf16x8 pa = *(const bf16x8*)&Pw[l16 * 40 + quad * 8];
#pragma unroll
    for (int nb = 0; nb < 8; nb++) {
      bf16x8 bv = *(const bf16x8*)&Vt[(nb * 16 + l16) * 40 + quad * 8];
      o[nb] = __builtin_amdgcn_mfma_f32_16x16x32_bf16(pa, bv, o[nb], 0, 0, 0);
    }
  }

  unsigned short* Op =
      out + ((size_t)((b * HH + h) * SS + q0 + quad * 4)) * HD + l16;
#pragma unroll
  for (int nb = 0; nb < 8; nb++)
#pragma unroll
    for (int r = 0; r < 4; r++)
      Op[(size_t)r * HD + nb * 16] = f2bf(o[nb][r] / l_r[r]);
}

// ---------------- launch ----------------
extern "C" void kernel_launch(void* const* d_in, const int* in_sizes, int n_in,
                              void* d_out, int out_size, void* d_ws, size_t ws_size,
                              hipStream_t stream) {
  const float* x = (const float*)d_in[0];
  const float* rms_w = (const float*)d_in[1];
  const float* w_qkv = (const float*)d_in[2];
  const float* w_out = (const float*)d_in[3];
  const float* w1 = (const float*)d_in[4];
  const float* b1 = (const float*)d_in[5];
  const float* w3 = (const float*)d_in[6];
  const float* b3 = (const float*)d_in[7];
  const float* w2 = (const float*)d_in[8];
  const float* b2 = (const float*)d_in[9];
  float* out = (float*)d_out;

  char* ws = (char*)d_ws;
  size_t off = 0;
  auto alloc = [&](size_t bytes) {
    char* p = ws + off;
    off += (bytes + 255) & ~(size_t)255;
    return p;
  };
  const int M = BB * SS;  // 4096
  unsigned short* wqkv_b = (unsigned short*)alloc((size_t)QKVD * DD * 2);
  unsigned short* wout_b = (unsigned short*)alloc((size_t)DD * DD * 2);
  unsigned short* w1_b = (unsigned short*)alloc((size_t)FF * DD * 2);
  unsigned short* w3_b = (unsigned short*)alloc((size_t)FF * DD * 2);
  unsigned short* w2_b = (unsigned short*)alloc((size_t)DD * FF * 2);
  unsigned short* xn_b = (unsigned short*)alloc((size_t)M * DD * 2);
  unsigned short* qkv_b = (unsigned short*)alloc((size_t)M * QKVD * 2);
  unsigned short* attn_b = (unsigned short*)alloc((size_t)M * DD * 2);
  unsigned short* h_b = (unsigned short*)alloc((size_t)M * DD * 2);
  unsigned short* act_b = (unsigned short*)alloc((size_t)M * FF * 2);

  // weight converts
  f32_to_bf16_vec<<<(QKVD * DD / 4) / 256, 256, 0, stream>>>(w_qkv, wqkv_b, QKVD * DD / 4);
  f32_to_bf16_vec<<<(DD * DD / 4) / 256, 256, 0, stream>>>(w_out, wout_b, DD * DD / 4);
  f32_to_bf16_vec<<<(FF * DD / 4) / 256, 256, 0, stream>>>(w1, w1_b, FF * DD / 4);
  f32_to_bf16_vec<<<(FF * DD / 4) / 256, 256, 0, stream>>>(w3, w3_b, FF * DD / 4);
  f32_to_bf16_vec<<<(DD * FF / 4) / 256, 256, 0, stream>>>(w2, w2_b, DD * FF / 4);

  // rmsnorm
  rmsnorm_bf16<<<M, 256, 0, stream>>>(x, rms_w, xn_b);

  // qkv = xn @ w_qkv^T
  gemm_bt<0><<<dim3(QKVD / 128, M / 128), 256, 0, stream>>>(
      xn_b, wqkv_b, qkv_b, nullptr, nullptr, nullptr, M, QKVD, DD);

  // attention
  attn_fwd<<<dim3(SS / 64, HH, BB), 256, 0, stream>>>(qkv_b, attn_b);

  // h = attn @ w_out^T
  gemm_bt<0><<<dim3(DD / 128, M / 128), 256, 0, stream>>>(
      attn_b, wout_b, h_b, nullptr, nullptr, nullptr, M, DD, DD);

  // act = h @ w1^T + b1
  gemm_bt<1><<<dim3(FF / 128, M / 128), 256, 0, stream>>>(
      h_b, w1_b, act_b, b1, nullptr, nullptr, M, FF, DD);

  // act = act + relu(h @ w3^T + b3)   (in-place aux read)
  gemm_bt<2><<<dim3(FF / 128, M / 128), 256, 0, stream>>>(
      h_b, w3_b, act_b, b3, act_b, nullptr, M, FF, DD);

  // out = act @ w2^T + b2 + x
  gemm_bt<3><<<dim3(DD / 128, M / 128), 256, 0, stream>>>(
      act_b, w2_b, out, b2, nullptr, x, M, DD, FF);
}

// Round 3
// 1572.037 us; speedup vs baseline: 1.0707x; 1.0707x over previous
//
#include <hip/hip_runtime.h>
#include <hip/hip_bf16.h>
#include <cstdint>

// Problem constants
#define BB 2
#define SS 2048
#define DD 2048
#define HH 16
#define HD 128
#define FF 8192
#define QKVD 6144  // 3*DD

typedef __bf16 bf16x8 __attribute__((ext_vector_type(8)));
typedef float floatx4 __attribute__((ext_vector_type(4)));

#define LOG2E 1.4426950408889634f

__device__ __forceinline__ unsigned short f2bf(float f) {
  unsigned u = __builtin_bit_cast(unsigned, f);
  u += 0x7FFFu + ((u >> 16) & 1u);
  return (unsigned short)(u >> 16);
}
__device__ __forceinline__ float bf2f(unsigned short h) {
  return __builtin_bit_cast(float, (unsigned)h << 16);
}

__device__ __forceinline__ void load_lds_16B(const void* g, void* l) {
  __builtin_amdgcn_global_load_lds(
      (const __attribute__((address_space(1))) unsigned int*)g,
      (__attribute__((address_space(3))) unsigned int*)l, 16, 0, 0);
}

// ---------------- fp32 -> bf16 convert ----------------
__global__ void f32_to_bf16_vec(const float* __restrict__ src,
                                unsigned short* __restrict__ dst, int n4) {
  int i = blockIdx.x * 256 + threadIdx.x;
  if (i < n4) {
    float4 v = ((const float4*)src)[i];
    ushort4 o;
    o.x = f2bf(v.x); o.y = f2bf(v.y); o.z = f2bf(v.z); o.w = f2bf(v.w);
    ((ushort4*)dst)[i] = o;
  }
}

// ---------------- RMSNorm (fp32 in, bf16 out) ----------------
__global__ __launch_bounds__(256) void rmsnorm_bf16(const float* __restrict__ x,
                                                    const float* __restrict__ w,
                                                    unsigned short* __restrict__ xn) {
  const int row = blockIdx.x, tid = threadIdx.x;
  const float4* xr = (const float4*)(x + (size_t)row * DD);
  float4 a = xr[tid], b = xr[tid + 256];
  float ss = a.x * a.x + a.y * a.y + a.z * a.z + a.w * a.w +
             b.x * b.x + b.y * b.y + b.z * b.z + b.w * b.w;
#pragma unroll
  for (int off = 1; off < 64; off <<= 1) ss += __shfl_xor(ss, off);
  __shared__ float red[4];
  if ((tid & 63) == 0) red[tid >> 6] = ss;
  __syncthreads();
  float tot = red[0] + red[1] + red[2] + red[3];
  float sc = rsqrtf(tot * (1.0f / (float)DD) + 1e-5f);
  const float4* wr = (const float4*)w;
  float4 wa = wr[tid], wb = wr[tid + 256];
  ushort4 oa, ob;
  oa.x = f2bf(a.x * sc * wa.x); oa.y = f2bf(a.y * sc * wa.y);
  oa.z = f2bf(a.z * sc * wa.z); oa.w = f2bf(a.w * sc * wa.w);
  ob.x = f2bf(b.x * sc * wb.x); ob.y = f2bf(b.y * sc * wb.y);
  ob.z = f2bf(b.z * sc * wb.z); ob.w = f2bf(b.w * sc * wb.w);
  *(ushort4*)&xn[(size_t)row * DD + tid * 4] = oa;
  *(ushort4*)&xn[(size_t)row * DD + (tid + 256) * 4] = ob;
}

// ---------------- GEMM: C[M,N] = A[M,K] @ Bw[N,K]^T  (bf16 in, fp32 acc) ----
// MODE 0: store bf16
// MODE 1: store bf16 of (acc + bias[col])
// MODE 2: store bf16 of (aux[idx] + relu(acc + bias[col]))   (aux may == Cout)
// MODE 3: store fp32 of (acc + bias[col] + res[idx])
template <int MODE>
__global__ __launch_bounds__(256) void gemm_bt(
    const unsigned short* __restrict__ A, const unsigned short* __restrict__ Bw,
    void* __restrict__ Cout, const float* __restrict__ bias,
    const unsigned short* __restrict__ aux, const float* __restrict__ res,
    int M, int N, int K) {
  __shared__ __align__(16) unsigned short As[128 * 32];
  __shared__ __align__(16) unsigned short Bs[128 * 32];
  const int tid = threadIdx.x;
  const int lane = tid & 63, wave = tid >> 6;
  const int l16 = lane & 15, quad = lane >> 4;
  const int wm = wave & 1, wn = wave >> 1;
  const int m0 = blockIdx.y * 128, n0 = blockIdx.x * 128;

  floatx4 acc[4][4];
#pragma unroll
  for (int i = 0; i < 4; i++)
#pragma unroll
    for (int j = 0; j < 4; j++) acc[i][j] = floatx4{0.f, 0.f, 0.f, 0.f};

  for (int k0 = 0; k0 < K; k0 += 32) {
    __syncthreads();
#pragma unroll
    for (int i = 0; i < 4; i++) {
      const int c = i * 256 + wave * 64 + lane;
      load_lds_16B(A + (size_t)(m0 + (c >> 2)) * K + k0 + (c & 3) * 8,
                   &As[(i * 256 + wave * 64) * 8]);
    }
#pragma unroll
    for (int i = 0; i < 4; i++) {
      const int c = i * 256 + wave * 64 + lane;
      load_lds_16B(Bw + (size_t)(n0 + (c >> 2)) * K + k0 + (c & 3) * 8,
                   &Bs[(i * 256 + wave * 64) * 8]);
    }
    __syncthreads();
    bf16x8 af[4], bfr[4];
#pragma unroll
    for (int mi = 0; mi < 4; mi++)
      af[mi] = *(const bf16x8*)&As[(wm * 64 + mi * 16 + l16) * 32 + quad * 8];
#pragma unroll
    for (int ni = 0; ni < 4; ni++)
      bfr[ni] = *(const bf16x8*)&Bs[(wn * 64 + ni * 16 + l16) * 32 + quad * 8];
#pragma unroll
    for (int mi = 0; mi < 4; mi++)
#pragma unroll
      for (int ni = 0; ni < 4; ni++)
        acc[mi][ni] = __builtin_amdgcn_mfma_f32_16x16x32_bf16(af[mi], bfr[ni],
                                                              acc[mi][ni], 0, 0, 0);
  }

#pragma unroll
  for (int ni = 0; ni < 4; ni++) {
    const int col = n0 + wn * 64 + ni * 16 + l16;
    float bv = 0.0f;
    if constexpr (MODE >= 1) bv = bias[col];
#pragma unroll
    for (int mi = 0; mi < 4; mi++) {
      const int row0 = m0 + wm * 64 + mi * 16 + quad * 4;
#pragma unroll
      for (int r = 0; r < 4; r++) {
        const size_t idx = (size_t)(row0 + r) * N + col;
        float v = acc[mi][ni][r];
        if constexpr (MODE == 0) {
          ((unsigned short*)Cout)[idx] = f2bf(v);
        } else if constexpr (MODE == 1) {
          ((unsigned short*)Cout)[idx] = f2bf(v + bv);
        } else if constexpr (MODE == 2) {
          float t = fmaxf(v + bv, 0.0f) + bf2f(aux[idx]);
          ((unsigned short*)Cout)[idx] = f2bf(t);
        } else {
          ((float*)Cout)[idx] = v + bv + res[idx];
        }
      }
    }
  }
}

// ---------------- Flash causal attention v3 ----------------
// Static balanced schedule: grid (8, H, B). Block p handles q-tiles {15-p, p}
// (each q-tile = 128 rows, 32 rows/wave). Work per pair = (2(15-p)+2)+(2p+2)=34
// KV tile-iters of 64 — identical for every block, no atomics.
// qkv: [B*S, 6144] bf16 rows (q|k|v per head). out: [B][H][S][HD] bf16.
__global__ __launch_bounds__(256) void attn_fwd(const unsigned short* __restrict__ qkv,
                                                unsigned short* __restrict__ out) {
  __shared__ __align__(16) unsigned short Ks[64 * 136];
  __shared__ __align__(16) unsigned short Vt[128 * 72];
  __shared__ __align__(16) unsigned short Ps[4][32 * 72];
  const int tid = threadIdx.x;
  const int lane = tid & 63, wave = tid >> 6;
  const int l16 = lane & 15, quad = lane >> 4;
  const int p = blockIdx.x, h = blockIdx.y, b = blockIdx.z;
  const float scale = 0.088388347648318447f;  // 1/sqrt(128)

#pragma unroll 1
  for (int pass = 0; pass < 2; pass++) {
    const int qt = pass == 0 ? 15 - p : p;  // heavy tile first
    const int q0w = qt * 128 + wave * 32;
    const int ntiles = 2 * qt + 2;

    // Q fragments: 32 rows x 128 cols, held for the whole pass
    bf16x8 aq[2][4];
#pragma unroll
    for (int mi = 0; mi < 2; mi++) {
      const unsigned short* Qp =
          qkv + (size_t)(b * SS + q0w + mi * 16 + l16) * QKVD + h * HD + quad * 8;
#pragma unroll
      for (int kc = 0; kc < 4; kc++) aq[mi][kc] = *(const bf16x8*)(Qp + kc * 32);
    }

    floatx4 o[2][8];
    float m_r[2][4], l_r[2][4];
#pragma unroll
    for (int mi = 0; mi < 2; mi++) {
#pragma unroll
      for (int nb = 0; nb < 8; nb++) o[mi][nb] = floatx4{0.f, 0.f, 0.f, 0.f};
#pragma unroll
      for (int r = 0; r < 4; r++) { m_r[mi][r] = -1e30f; l_r[mi][r] = 0.f; }
    }

#pragma unroll 1
    for (int t = 0; t < ntiles; t++) {
      const int kv0 = t * 64;
      const bool need_mask = (t >= ntiles - 2);
      __syncthreads();  // also protects LDS reuse across t / pass
      {
        const int cc = tid & 15;
#pragma unroll
        for (int i = 0; i < 4; i++) {
          const int r = (tid >> 4) + 16 * i;
          const size_t rowb = (size_t)(b * SS + kv0 + r) * QKVD + h * HD + cc * 8;
          *(uint4*)&Ks[r * 136 + cc * 8] = *(const uint4*)(qkv + rowb + DD);
          unsigned short tmp[8];
          *(uint4*)tmp = *(const uint4*)(qkv + rowb + 2 * DD);
          // V^T with chunk-rotation swizzle: Vt[d][kv] at chunk ((kv>>3)+(d>>3))&7
#pragma unroll
          for (int j2 = 0; j2 < 8; j2++) {
            const int d = cc * 8 + j2;
            Vt[d * 72 + (((r >> 3) + (d >> 3)) & 7) * 8 + (r & 7)] = tmp[j2];
          }
        }
      }
      __syncthreads();

      // S = Q K^T  (32q x 64kv)
      floatx4 s[2][4];
#pragma unroll
      for (int mi = 0; mi < 2; mi++)
#pragma unroll
        for (int ni = 0; ni < 4; ni++) s[mi][ni] = floatx4{0.f, 0.f, 0.f, 0.f};
#pragma unroll
      for (int kc = 0; kc < 4; kc++) {
        bf16x8 bk[4];
#pragma unroll
        for (int ni = 0; ni < 4; ni++)
          bk[ni] = *(const bf16x8*)&Ks[(ni * 16 + l16) * 136 + kc * 32 + quad * 8];
#pragma unroll
        for (int mi = 0; mi < 2; mi++)
#pragma unroll
          for (int ni = 0; ni < 4; ni++)
            s[mi][ni] = __builtin_amdgcn_mfma_f32_16x16x32_bf16(aq[mi][kc], bk[ni],
                                                                s[mi][ni], 0, 0, 0);
      }

      // online softmax
#pragma unroll
      for (int mi = 0; mi < 2; mi++) {
        float alpha[4];
#pragma unroll
        for (int r = 0; r < 4; r++) {
          const int qrow = q0w + mi * 16 + quad * 4 + r;
          float v[4];
#pragma unroll
          for (int ni = 0; ni < 4; ni++) {
            v[ni] = s[mi][ni][r] * scale;
            if (need_mask && (kv0 + ni * 16 + l16 > qrow)) v[ni] = -1e30f;
          }
          float mx = fmaxf(fmaxf(v[0], v[1]), fmaxf(v[2], v[3]));
          mx = fmaxf(mx, __shfl_xor(mx, 1));
          mx = fmaxf(mx, __shfl_xor(mx, 2));
          mx = fmaxf(mx, __shfl_xor(mx, 4));
          mx = fmaxf(mx, __shfl_xor(mx, 8));
          const float mnew = fmaxf(m_r[mi][r], mx);
          alpha[r] = exp2f((m_r[mi][r] - mnew) * LOG2E);
          m_r[mi][r] = mnew;
          float rs = 0.f;
#pragma unroll
          for (int ni = 0; ni < 4; ni++) {
            v[ni] = exp2f((v[ni] - mnew) * LOG2E);
            rs += v[ni];
          }
          rs += __shfl_xor(rs, 1);
          rs += __shfl_xor(rs, 2);
          rs += __shfl_xor(rs, 4);
          rs += __shfl_xor(rs, 8);
          l_r[mi][r] = l_r[mi][r] * alpha[r] + rs;
          unsigned short* Pw = &Ps[wave][(mi * 16 + quad * 4 + r) * 72 + l16];
#pragma unroll
          for (int ni = 0; ni < 4; ni++) Pw[ni * 16] = f2bf(v[ni]);
        }
#pragma unroll
        for (int nb = 0; nb < 8; nb++)
#pragma unroll
          for (int r = 0; r < 4; r++) o[mi][nb][r] *= alpha[r];
      }
      asm volatile("s_waitcnt lgkmcnt(0)" ::: "memory");  // Ps is wave-private

      // O += P V
      bf16x8 pa[2][2];
#pragma unroll
      for (int mi = 0; mi < 2; mi++)
#pragma unroll
        for (int kc2 = 0; kc2 < 2; kc2++)
          pa[mi][kc2] =
              *(const bf16x8*)&Ps[wave][(mi * 16 + l16) * 72 + kc2 * 32 + quad * 8];
#pragma unroll
      for (int nb = 0; nb < 8; nb++) {
        const int d = nb * 16 + l16;
#pragma unroll
        for (int kc2 = 0; kc2 < 2; kc2++) {
          const int chunk = kc2 * 4 + quad;
          bf16x8 bv = *(const bf16x8*)&Vt[d * 72 + ((chunk + (d >> 3)) & 7) * 8];
#pragma unroll
          for (int mi = 0; mi < 2; mi++)
            o[mi][nb] = __builtin_amdgcn_mfma_f32_16x16x32_bf16(pa[mi][kc2], bv,
                                                                o[mi][nb], 0, 0, 0);
        }
      }
    }

    // epilogue: out[b][h][row][d] = o / l
#pragma unroll
    for (int mi = 0; mi < 2; mi++) {
      unsigned short* Op =
          out + (size_t)((b * HH + h) * SS + q0w + mi * 16 + quad * 4) * HD + l16;
#pragma unroll
      for (int nb = 0; nb < 8; nb++)
#pragma unroll
        for (int r = 0; r < 4; r++)
          Op[(size_t)r * HD + nb * 16] = f2bf(o[mi][nb][r] / l_r[mi][r]);
    }
  }
}

// ---------------- launch ----------------
extern "C" void kernel_launch(void* const* d_in, const int* in_sizes, int n_in,
                              void* d_out, int out_size, void* d_ws, size_t ws_size,
                              hipStream_t stream) {
  const float* x = (const float*)d_in[0];
  const float* rms_w = (const float*)d_in[1];
  const float* w_qkv = (const float*)d_in[2];
  const float* w_out = (const float*)d_in[3];
  const float* w1 = (const float*)d_in[4];
  const float* b1 = (const float*)d_in[5];
  const float* w3 = (const float*)d_in[6];
  const float* b3 = (const float*)d_in[7];
  const float* w2 = (const float*)d_in[8];
  const float* b2 = (const float*)d_in[9];
  float* out = (float*)d_out;

  char* ws = (char*)d_ws;
  size_t off = 0;
  auto alloc = [&](size_t bytes) {
    char* p = ws + off;
    off += (bytes + 255) & ~(size_t)255;
    return p;
  };
  const int M = BB * SS;  // 4096
  unsigned short* wqkv_b = (unsigned short*)alloc((size_t)QKVD * DD * 2);
  unsigned short* wout_b = (unsigned short*)alloc((size_t)DD * DD * 2);
  unsigned short* w1_b = (unsigned short*)alloc((size_t)FF * DD * 2);
  unsigned short* w3_b = (unsigned short*)alloc((size_t)FF * DD * 2);
  unsigned short* w2_b = (unsigned short*)alloc((size_t)DD * FF * 2);
  unsigned short* xn_b = (unsigned short*)alloc((size_t)M * DD * 2);
  unsigned short* qkv_b = (unsigned short*)alloc((size_t)M * QKVD * 2);
  unsigned short* attn_b = (unsigned short*)alloc((size_t)M * DD * 2);
  unsigned short* h_b = (unsigned short*)alloc((size_t)M * DD * 2);
  unsigned short* act_b = (unsigned short*)alloc((size_t)M * FF * 2);

  // weight converts
  f32_to_bf16_vec<<<(QKVD * DD / 4) / 256, 256, 0, stream>>>(w_qkv, wqkv_b, QKVD * DD / 4);
  f32_to_bf16_vec<<<(DD * DD / 4) / 256, 256, 0, stream>>>(w_out, wout_b, DD * DD / 4);
  f32_to_bf16_vec<<<(FF * DD / 4) / 256, 256, 0, stream>>>(w1, w1_b, FF * DD / 4);
  f32_to_bf16_vec<<<(FF * DD / 4) / 256, 256, 0, stream>>>(w3, w3_b, FF * DD / 4);
  f32_to_bf16_vec<<<(DD * FF / 4) / 256, 256, 0, stream>>>(w2, w2_b, DD * FF / 4);

  // rmsnorm
  rmsnorm_bf16<<<M, 256, 0, stream>>>(x, rms_w, xn_b);

  // qkv = xn @ w_qkv^T
  gemm_bt<0><<<dim3(QKVD / 128, M / 128), 256, 0, stream>>>(
      xn_b, wqkv_b, qkv_b, nullptr, nullptr, nullptr, M, QKVD, DD);

  // attention (static balanced schedule, 256 blocks)
  attn_fwd<<<dim3(8, HH, BB), 256, 0, stream>>>(qkv_b, attn_b);

  // h = attn @ w_out^T
  gemm_bt<0><<<dim3(DD / 128, M / 128), 256, 0, stream>>>(
      attn_b, wout_b, h_b, nullptr, nullptr, nullptr, M, DD, DD);

  // act = h @ w1^T + b1
  gemm_bt<1><<<dim3(FF / 128, M / 128), 256, 0, stream>>>(
      h_b, w1_b, act_b, b1, nullptr, nullptr, M, FF, DD);

  // act = act + relu(h @ w3^T + b3)   (in-place aux read)
  gemm_bt<2><<<dim3(FF / 128, M / 128), 256, 0, stream>>>(
      h_b, w3_b, act_b, b3, act_b, nullptr, M, FF, DD);

  // out = act @ w2^T + b2 + x
  gemm_bt<3><<<dim3(DD / 128, M / 128), 256, 0, stream>>>(
      act_b, w2_b, out, b2, nullptr, x, M, DD, FF);
}